// Round 1
// baseline (4196.953 us; speedup 1.0000x reference)
//
#include <hip/hip_runtime.h>
#include <hip/hip_fp16.h>
#include <hip/hip_cooperative_groups.h>

typedef _Float16 f16;
typedef _Float16 half8 __attribute__((ext_vector_type(8)));
typedef _Float16 f16x4 __attribute__((ext_vector_type(4)));
typedef float floatx4 __attribute__((ext_vector_type(4)));
typedef unsigned long long u64;

#define BATCH 64
#define SEQ 512
#define EMB 512
#define HID 1024

// ws layout (bytes):
//   [0, 524288)        LL state slots: 4 groups x 2 parity x 8192 u64 words
//                      word = { tag:u32 (hi) , 2 x f16 state data (lo) }
//   [524288, 2621440)  W16: W_aa as f16, 1M elements
// LL protocol: producer of step s stores words tagged (s+1) into slot (s+1)&1,
// fire-and-forget (relaxed agent atomics, no drain, no flag, no arrive).
// Consumer at step s polls its own 16 words of slot s&1 for tag==s.
// 2-slot safety: P writes a[s+1] only after its polls saw ALL tag-s words;
// any WG issues tag-s stores only after its post-staging barrier, i.e. after
// it fully read a[s-1] out of slot (s+1)&1. Re-run safety: k0 re-zeros both
// slots (tag 0) before every k2 launch; within a run each thread re-polls the
// same word and witnesses tags monotonically, so stale higher tags are
// overwritten before they could be polled for.
#define WS_WORDS 65536        // 4 groups * 2 slots * 8192 words
#define W16_OFF_HALFS 262144  // 524288 / 2

// ---------------- K0: convert W_aa fp32->f16; zero all LL slots --------------
__global__ __launch_bounds__(256) void k0_cvt_waa(const float* __restrict__ W,
                                                  f16* __restrict__ W16,
                                                  u64* __restrict__ wsw) {
    int gtid = blockIdx.x * 256 + threadIdx.x;  // 0..262143
    int i = gtid * 4;
    float4 v = *(const float4*)(W + i);
    f16x4 h;
    h[0] = (f16)v.x; h[1] = (f16)v.y; h[2] = (f16)v.z; h[3] = (f16)v.w;
    *(f16x4*)(W16 + i) = h;
    if (gtid < WS_WORDS) wsw[gtid] = 0ull;
}

// ---------------- K1: xproj = X @ W_ax^T + b_a -> d_out[s][b][h] -------------
// fp16 split-2 on X, single f16 W_ax. 64x64 tile, 4 waves 2x2. (validated R1)
__global__ __launch_bounds__(256) void k1_xproj(const float* __restrict__ X,
                                                const float* __restrict__ Wax,
                                                const float* __restrict__ ba,
                                                float* __restrict__ out) {
    __shared__ __align__(16) f16 Xhi[64][40];
    __shared__ __align__(16) f16 Xlo[64][40];
    __shared__ __align__(16) f16 Wh[64][40];
    const int tid  = threadIdx.x;
    const int lane = tid & 63;
    const int wave = tid >> 6;
    const int vm = wave >> 1, vn = wave & 1;
    const int m0 = blockIdx.x * 64;   // m = b*512 + s
    const int n0 = blockIdx.y * 64;   // n = h
    const int q = lane >> 4, c = lane & 15;
    const int srow = tid >> 2, scol = (tid & 3) * 8;

    floatx4 acc[2][2] = {};

    for (int kc = 0; kc < EMB; kc += 32) {
        const float* xp = X + (size_t)(m0 + srow) * EMB + kc + scol;
        float4 x0 = *(const float4*)xp;
        float4 x1 = *(const float4*)(xp + 4);
        float xv[8] = {x0.x, x0.y, x0.z, x0.w, x1.x, x1.y, x1.z, x1.w};
        half8 xh, xl;
#pragma unroll
        for (int j = 0; j < 8; j++) {
            f16 h = (f16)xv[j];
            xh[j] = h;
            xl[j] = (f16)(xv[j] - (float)h);
        }
        *(half8*)&Xhi[srow][scol] = xh;
        *(half8*)&Xlo[srow][scol] = xl;
        const float* wp = Wax + (size_t)(n0 + srow) * EMB + kc + scol;
        float4 w0 = *(const float4*)wp;
        float4 w1 = *(const float4*)(wp + 4);
        float wv[8] = {w0.x, w0.y, w0.z, w0.w, w1.x, w1.y, w1.z, w1.w};
        half8 wh8;
#pragma unroll
        for (int j = 0; j < 8; j++) wh8[j] = (f16)wv[j];
        *(half8*)&Wh[srow][scol] = wh8;
        __syncthreads();

#pragma unroll
        for (int im = 0; im < 2; im++) {
            half8 ahi = *(const half8*)&Xhi[vm * 32 + im * 16 + c][q * 8];
            half8 alo = *(const half8*)&Xlo[vm * 32 + im * 16 + c][q * 8];
#pragma unroll
            for (int in = 0; in < 2; in++) {
                half8 bf = *(const half8*)&Wh[vn * 32 + in * 16 + c][q * 8];
                acc[im][in] = __builtin_amdgcn_mfma_f32_16x16x32_f16(ahi, bf, acc[im][in], 0, 0, 0);
                acc[im][in] = __builtin_amdgcn_mfma_f32_16x16x32_f16(alo, bf, acc[im][in], 0, 0, 0);
            }
        }
        __syncthreads();
    }
#pragma unroll
    for (int im = 0; im < 2; im++) {
#pragma unroll
        for (int in = 0; in < 2; in++) {
            int n = n0 + vn * 32 + in * 16 + c;
            float bias = ba[n];
#pragma unroll
            for (int r = 0; r < 4; r++) {
                int m = m0 + vm * 32 + im * 16 + q * 4 + r;
                int b = m >> 9, s = m & 511;
                out[(size_t)(s * BATCH + b) * HID + n] = acc[im][in][r] + bias;
            }
        }
    }
}

// LDS-only barrier: drains DS ops, leaves global loads/stores in flight.
#define LBAR()                                                \
    do {                                                      \
        asm volatile("s_waitcnt lgkmcnt(0)" ::: "memory");    \
        __builtin_amdgcn_s_barrier();                         \
        asm volatile("" ::: "memory");                        \
    } while (0)

// ---------------- K2: scan, LL tagged-word state exchange --------------------
// 32 WGs x 512 thr. group = blockIdx/8 (b0=group*16), wig = (blockIdx%8)*8+wave,
// j0 = wig*16. W_aa rows resident in registers (32 x half8 per lane).
// State exchanged as 8B {tag,data} words; consumers poll their own words.
__global__ __launch_bounds__(512, 1) void k2_scan(const f16* __restrict__ W16,
                                                  float* __restrict__ out,
                                                  u64* __restrict__ wsw) {
    __shared__ __align__(16) f16 S[16][1032];  // +8 pad
    const int tid  = threadIdx.x;
    const int lane = tid & 63;
    const int wave = tid >> 6;                        // 0..7
    const int grp  = blockIdx.x >> 3;                 // 0..3
    const int wig  = ((blockIdx.x & 7) << 3) + wave;  // 0..63
    const int j0   = wig << 4;
    const int b0   = grp << 4;
    const int q = lane >> 4, c = lane & 15;

    // A-operand (W) fragments resident for the whole scan:
    // lane holds W[j0+c][t*32 + q*8 .. +7] for t=0..31
    half8 w[32];
    {
        const f16* Wrow = W16 + (size_t)(j0 + c) * HID + q * 8;
#pragma unroll
        for (int t = 0; t < 32; t++) w[t] = *(const half8*)(Wrow + t * 32);
    }
    u64* const slot0 = wsw + (size_t)grp * 16384;  // 8192 words per slot
    u64* const slot1 = slot0 + 8192;
    const int b = b0 + c;
    // producer word index: f16 idx = c*1024 + j0 + q*4  ->  /2
    const int wsel = c * 512 + (j0 >> 1) + (q << 1);

    for (int s = 0; s < SEQ; s++) {
        u64* const src = (s & 1) ? slot1 : slot0;
        u64* const dst = (s & 1) ? slot0 : slot1;
        // prefetch xp (regular cached load; consumed in epilogue)
        size_t obase = ((size_t)s * BATCH + b) * HID + j0 + (q << 2);
        float4 xp = *(const float4*)(out + obase);

        // ---- LL poll-stage: 16 words/thread, word w=it*512+tid covers
        //      batch it, state cols {2*tid, 2*tid+1} ----
        {
            const u64* sw = src + tid;
            const unsigned stag = (unsigned)s;
            u64 vv[16];
            unsigned pend = 0xFFFFu;
#pragma unroll
            for (int it = 0; it < 16; it++)
                vv[it] = __hip_atomic_load(sw + it * 512, __ATOMIC_RELAXED,
                                           __HIP_MEMORY_SCOPE_AGENT);
            while (pend) {
#pragma unroll
                for (int it = 0; it < 16; it++) {
                    if (pend & (1u << it)) {
                        if ((unsigned)(vv[it] >> 32) == stag) {
                            *(unsigned*)&S[it][tid << 1] = (unsigned)vv[it];
                            pend &= ~(1u << it);
                        } else {
                            vv[it] = __hip_atomic_load(sw + it * 512, __ATOMIC_RELAXED,
                                                       __HIP_MEMORY_SCOPE_AGENT);
                        }
                    }
                }
            }
        }
        LBAR();  // staging LDS writes -> visible to all waves; stores stay in flight

        // ---- K-loop: 32 chunks, W from regs, B-frag from LDS ----
        floatx4 acc = {0.f, 0.f, 0.f, 0.f};
#pragma unroll
        for (int t = 0; t < 32; t++) {
            half8 bfrag = *(const half8*)&S[c][t * 32 + q * 8];
            acc = __builtin_amdgcn_mfma_f32_16x16x32_f16(w[t], bfrag, acc, 0, 0, 0);
        }

        // ---- epilogue: lane l reg r -> j = j0+q*4+r, b = b0+c ----
        float4 v;
        v.x = tanhf(xp.x + acc[0]);
        v.y = tanhf(xp.y + acc[1]);
        v.z = tanhf(xp.z + acc[2]);
        v.w = tanhf(xp.w + acc[3]);
        *(float4*)(out + obase) = v;
        union { f16 h[2]; unsigned u; } p0, p1;
        p0.h[0] = (f16)v.x; p0.h[1] = (f16)v.y;
        p1.h[0] = (f16)v.z; p1.h[1] = (f16)v.w;
        const u64 t64 = ((u64)(unsigned)(s + 1)) << 32;
        __hip_atomic_store(dst + wsel,     t64 | (u64)p0.u, __ATOMIC_RELAXED,
                           __HIP_MEMORY_SCOPE_AGENT);
        __hip_atomic_store(dst + wsel + 1, t64 | (u64)p1.u, __ATOMIC_RELAXED,
                           __HIP_MEMORY_SCOPE_AGENT);
        if (s == SEQ - 1)
            *(float4*)(out + (size_t)SEQ * BATCH * HID + (size_t)b * HID + j0 + (q << 2)) = v;

        // ---- LDS WAR barrier before next step's staging overwrites S;
        //      crucially does NOT drain vmcnt (stores propagate while we poll)
        LBAR();
    }
}

extern "C" void kernel_launch(void* const* d_in, const int* in_sizes, int n_in,
                              void* d_out, int out_size, void* d_ws, size_t ws_size,
                              hipStream_t stream) {
    const float* X   = (const float*)d_in[0];
    const float* Wax = (const float*)d_in[1];
    const float* Waa = (const float*)d_in[2];
    const float* ba  = (const float*)d_in[3];
    float* out = (float*)d_out;

    u64* wsw = (u64*)d_ws;
    f16* W16 = (f16*)d_ws + W16_OFF_HALFS;

    k0_cvt_waa<<<dim3(HID * HID / 1024), dim3(256), 0, stream>>>(Waa, W16, wsw);
    k1_xproj<<<dim3((BATCH * SEQ) / 64, HID / 64), dim3(256), 0, stream>>>(X, Wax, ba, out);

    void* args[] = {(void*)&W16, (void*)&out, (void*)&wsw};
    hipLaunchCooperativeKernel((void*)k2_scan, dim3(32), dim3(512), args, 0, stream);
}

// Round 6
// 2199.716 us; speedup vs baseline: 1.9080x; 1.9080x over previous
//
#include <hip/hip_runtime.h>
#include <hip/hip_fp16.h>
#include <hip/hip_cooperative_groups.h>

typedef _Float16 f16;
typedef _Float16 half8 __attribute__((ext_vector_type(8)));
typedef _Float16 f16x4 __attribute__((ext_vector_type(4)));
typedef float floatx4 __attribute__((ext_vector_type(4)));
typedef unsigned long long u64;

#define BATCH 64
#define SEQ 512
#define EMB 512
#define HID 1024
#define GWG 8  // workgroups per b-group (512 threads each -> 64 waves/group)

// ws layout (bytes):
//   [0, 262144)          abuf: 4 groups x 2 parity x 16384 f16 (state, single f16 plane)
//   [262144, 2359296)    W16: W_aa as f16, 1M elements
//   [2359296, +1KB)      barrier counters, 4 x u32 at 256B stride
#define ABUF_HALFS 131072
#define BAR_OFF 2359296

// ---------------- K0: convert W_aa fp32->f16; zero state buf0 + counters -----
__global__ __launch_bounds__(256) void k0_cvt_waa(const float* __restrict__ W,
                                                  f16* __restrict__ W16,
                                                  f16* __restrict__ abuf,
                                                  unsigned* __restrict__ bar) {
    int gtid = blockIdx.x * 256 + threadIdx.x;  // 0..262143
    int i = gtid * 4;
    float4 v = *(const float4*)(W + i);
    f16x4 h;
    h[0] = (f16)v.x; h[1] = (f16)v.y; h[2] = (f16)v.z; h[3] = (f16)v.w;
    *(f16x4*)(W16 + i) = h;
    // zero parity-0 state buffers: group g dwords [g*16384, g*16384+8192)
    if (gtid < 32768) {
        int g = gtid >> 13, off = gtid & 8191;
        ((unsigned*)abuf)[g * 16384 + off] = 0u;
    }
    if (gtid < 4) bar[gtid * 64] = 0u;
}

// ---------------- K1: xproj = X @ W_ax^T + b_a -> d_out[s][b][h] -------------
// fp16 split-2 on X, single f16 W_ax. 64x64 tile, 4 waves 2x2. (validated R1)
__global__ __launch_bounds__(256) void k1_xproj(const float* __restrict__ X,
                                                const float* __restrict__ Wax,
                                                const float* __restrict__ ba,
                                                float* __restrict__ out) {
    __shared__ __align__(16) f16 Xhi[64][40];
    __shared__ __align__(16) f16 Xlo[64][40];
    __shared__ __align__(16) f16 Wh[64][40];
    const int tid  = threadIdx.x;
    const int lane = tid & 63;
    const int wave = tid >> 6;
    const int vm = wave >> 1, vn = wave & 1;
    const int m0 = blockIdx.x * 64;   // m = b*512 + s
    const int n0 = blockIdx.y * 64;   // n = h
    const int q = lane >> 4, c = lane & 15;
    const int srow = tid >> 2, scol = (tid & 3) * 8;

    floatx4 acc[2][2] = {};

    for (int kc = 0; kc < EMB; kc += 32) {
        const float* xp = X + (size_t)(m0 + srow) * EMB + kc + scol;
        float4 x0 = *(const float4*)xp;
        float4 x1 = *(const float4*)(xp + 4);
        float xv[8] = {x0.x, x0.y, x0.z, x0.w, x1.x, x1.y, x1.z, x1.w};
        half8 xh, xl;
#pragma unroll
        for (int j = 0; j < 8; j++) {
            f16 h = (f16)xv[j];
            xh[j] = h;
            xl[j] = (f16)(xv[j] - (float)h);
        }
        *(half8*)&Xhi[srow][scol] = xh;
        *(half8*)&Xlo[srow][scol] = xl;
        const float* wp = Wax + (size_t)(n0 + srow) * EMB + kc + scol;
        float4 w0 = *(const float4*)wp;
        float4 w1 = *(const float4*)(wp + 4);
        float wv[8] = {w0.x, w0.y, w0.z, w0.w, w1.x, w1.y, w1.z, w1.w};
        half8 wh8;
#pragma unroll
        for (int j = 0; j < 8; j++) wh8[j] = (f16)wv[j];
        *(half8*)&Wh[srow][scol] = wh8;
        __syncthreads();

#pragma unroll
        for (int im = 0; im < 2; im++) {
            half8 ahi = *(const half8*)&Xhi[vm * 32 + im * 16 + c][q * 8];
            half8 alo = *(const half8*)&Xlo[vm * 32 + im * 16 + c][q * 8];
#pragma unroll
            for (int in = 0; in < 2; in++) {
                half8 bf = *(const half8*)&Wh[vn * 32 + in * 16 + c][q * 8];
                acc[im][in] = __builtin_amdgcn_mfma_f32_16x16x32_f16(ahi, bf, acc[im][in], 0, 0, 0);
                acc[im][in] = __builtin_amdgcn_mfma_f32_16x16x32_f16(alo, bf, acc[im][in], 0, 0, 0);
            }
        }
        __syncthreads();
    }
#pragma unroll
    for (int im = 0; im < 2; im++) {
#pragma unroll
        for (int in = 0; in < 2; in++) {
            int n = n0 + vn * 32 + in * 16 + c;
            float bias = ba[n];
#pragma unroll
            for (int r = 0; r < 4; r++) {
                int m = m0 + vm * 32 + im * 16 + q * 4 + r;
                int b = m >> 9, s = m & 511;
                out[(size_t)(s * BATCH + b) * HID + n] = acc[im][in][r] + bias;
            }
        }
    }
}

// ---------------- K2: scan, fence-free state exchange ------------------------
// 32 WGs x 512 thr. group = blockIdx/8 (b0=group*16), wig = (blockIdx%8)*8+wave,
// j0 = wig*16. W_aa rows in registers (32 x half8). State single f16, double-
// buffered; exchanged via RELAXED AGENT-scope 8B atomics (L1/L2-bypassing, no
// cache-wide fences). Arrival: s_waitcnt vmcnt(0) -> syncthreads -> atomicAdd.
// (R0-verbatim protocol; only the staging loop is batched: all 8 loads issued
// into registers first, then written to LDS -> the 8 IF round trips overlap.)
__global__ __launch_bounds__(512, 1) void k2_scan(const f16* __restrict__ W16,
                                                  float* __restrict__ out,
                                                  f16* __restrict__ abuf,
                                                  unsigned* __restrict__ bar) {
    __shared__ __align__(16) f16 S[16][1032];  // +8 pad
    const int tid  = threadIdx.x;
    const int lane = tid & 63;
    const int wave = tid >> 6;                        // 0..7
    const int grp  = blockIdx.x >> 3;                 // 0..3
    const int wig  = ((blockIdx.x & 7) << 3) + wave;  // 0..63
    const int j0   = wig << 4;
    const int b0   = grp << 4;
    const int q = lane >> 4, c = lane & 15;

    // A-operand (W) fragments resident for the whole scan:
    // lane holds W[j0+c][t*32 + q*8 .. +7] for t=0..31
    half8 w[32];
    {
        const f16* Wrow = W16 + (size_t)(j0 + c) * HID + q * 8;
#pragma unroll
        for (int t = 0; t < 32; t++) w[t] = *(const half8*)(Wrow + t * 32);
    }
    unsigned* cnt = bar + grp * 64;
    f16* const buf0 = abuf + (size_t)grp * 32768;
    f16* const buf1 = buf0 + 16384;

    for (int s = 0; s < SEQ; s++) {
        const f16* src = (s & 1) ? buf1 : buf0;
        f16* dst       = (s & 1) ? buf0 : buf1;
        // prefetch xp (independent of barrier; hides HBM latency under spin)
        const int b = b0 + c;
        size_t obase = ((size_t)s * BATCH + b) * HID + j0 + (q << 2);
        float4 xp = *(const float4*)(out + obase);
        // ---- wait: state for step s ready when cnt >= 8*s ----
        if (tid == 0) {
            unsigned tgt = (unsigned)(GWG * s);
            while (__hip_atomic_load(cnt, __ATOMIC_RELAXED, __HIP_MEMORY_SCOPE_AGENT) < tgt) {}
        }
        __syncthreads();
        // ---- stage state (16384 f16 = 32 KB): batch all 8 loads in flight,
        //      then write LDS (was: load->write per iter = 8 serial IF RTTs) ----
        {
            u64 tmp[8];
#pragma unroll
            for (int it = 0; it < 8; it++)
                tmp[it] = __hip_atomic_load((const u64*)(src + (it * 512 + tid) * 4),
                                            __ATOMIC_RELAXED, __HIP_MEMORY_SCOPE_AGENT);
#pragma unroll
            for (int it = 0; it < 8; it++) {
                int idx = (it * 512 + tid) * 4;  // half index, 8B chunks
                *(u64*)&S[idx >> 10][idx & 1023] = tmp[it];
            }
        }
        __syncthreads();
        // ---- K-loop: 32 chunks, W from regs, B-frag from LDS ----
        floatx4 acc = {0.f, 0.f, 0.f, 0.f};
#pragma unroll
        for (int t = 0; t < 32; t++) {
            half8 bfrag = *(const half8*)&S[c][t * 32 + q * 8];
            acc = __builtin_amdgcn_mfma_f32_16x16x32_f16(w[t], bfrag, acc, 0, 0, 0);
        }
        // ---- epilogue: lane l reg r -> j = j0+q*4+r, b = b0+c ----
        float4 v;
        v.x = tanhf(xp.x + acc[0]);
        v.y = tanhf(xp.y + acc[1]);
        v.z = tanhf(xp.z + acc[2]);
        v.w = tanhf(xp.w + acc[3]);
        *(float4*)(out + obase) = v;
        union { f16x4 h; u64 u; } cv;
        cv.h[0] = (f16)v.x; cv.h[1] = (f16)v.y; cv.h[2] = (f16)v.z; cv.h[3] = (f16)v.w;
        __hip_atomic_store((u64*)(dst + c * 1024 + j0 + (q << 2)), cv.u,
                           __ATOMIC_RELAXED, __HIP_MEMORY_SCOPE_AGENT);
        if (s == SEQ - 1)
            *(float4*)(out + (size_t)SEQ * BATCH * HID + (size_t)b * HID + j0 + (q << 2)) = v;
        // ---- arrive: drain own stores, whole-WG rendezvous, then count up ----
        asm volatile("s_waitcnt vmcnt(0)" ::: "memory");
        __syncthreads();
        if (tid == 0)
            __hip_atomic_fetch_add(cnt, 1u, __ATOMIC_RELAXED, __HIP_MEMORY_SCOPE_AGENT);
    }
}

extern "C" void kernel_launch(void* const* d_in, const int* in_sizes, int n_in,
                              void* d_out, int out_size, void* d_ws, size_t ws_size,
                              hipStream_t stream) {
    const float* X   = (const float*)d_in[0];
    const float* Wax = (const float*)d_in[1];
    const float* Waa = (const float*)d_in[2];
    const float* ba  = (const float*)d_in[3];
    float* out = (float*)d_out;

    f16* abuf = (f16*)d_ws;
    f16* W16  = abuf + ABUF_HALFS;
    unsigned* bar = (unsigned*)((char*)d_ws + BAR_OFF);

    k0_cvt_waa<<<dim3(HID * HID / 1024), dim3(256), 0, stream>>>(Waa, W16, abuf, bar);
    k1_xproj<<<dim3((BATCH * SEQ) / 64, HID / 64), dim3(256), 0, stream>>>(X, Wax, ba, out);

    void* args[] = {(void*)&W16, (void*)&out, (void*)&abuf, (void*)&bar};
    hipLaunchCooperativeKernel((void*)k2_scan, dim3(32), dim3(512), args, 0, stream);
}